// Round 16
// baseline (299.764 us; speedup 1.0000x reference)
//
#include <hip/hip_runtime.h>
#include <cstdint>
#include <cstddef>

#define H 8
#define DHID 128
#define XST 144          // xs row stride in shorts: 128 bf16 msg + 8 f32 scores (288B)
#define BM 64            // rows per MFMA block
#define LDST 136         // padded LDS row stride (bf16 elems)
#define NEG_SLOPE 0.2f
#define GN_EPS 1e-5f

#define SCAN_T 256
#define SCAN_I 4         // 1024 elements per scan block; requires 2*Np <= 256*1024

typedef __attribute__((ext_vector_type(8))) short short8;
typedef __attribute__((ext_vector_type(4))) float f32x4;

__device__ __forceinline__ void atomAddF(float* p, float v) {
    __hip_atomic_fetch_add(p, v, __ATOMIC_RELAXED, __HIP_MEMORY_SCOPE_AGENT);
}
__device__ __forceinline__ unsigned short f2bf(float f) {
    uint32_t u = __float_as_uint(f);
    uint32_t r = (u + 0x7FFFu + ((u >> 16) & 1u)) >> 16;
    return (unsigned short)r;
}
__device__ __forceinline__ uint32_t pack2bf(float lo, float hi) {
    return (uint32_t)f2bf(lo) | ((uint32_t)f2bf(hi) << 16);
}
__device__ __forceinline__ float bflo(uint32_t v) { return __uint_as_float(v << 16); }
__device__ __forceinline__ float bfhi(uint32_t v) { return __uint_as_float(v & 0xFFFF0000u); }

// ---------------------------------------------------------------------------
// K1: prep (pack weights -> MFMA B-frags, attention fold inline, misc init)
//     ∥ deg_hist (real edges; MLP-8; records per-edge rank).
// ---------------------------------------------------------------------------
struct PrepHist {
    const float *Wlp, *Wsc, *Wla, *Wsw, *W2p;
    const float *Wdw, *adw, *asc_, *Wdc, *adc_, *asw_;
    unsigned short *WlinP_p, *WsrcP_c, *WlinP_a, *WsrcP_w, *W2P_p, *VscP_p, *VscP_a;
    const float *bw, *bc, *gnb_a, *W2a, *b2a;
    float *bsum, *row_a, *colsum, *colsumsq;
    unsigned short *xs_w_ph, *xs_c_ph;   // phantom row bases
    const int *dst_w, *dst_c;
    int *deg, *rank;
    int Ew, Ec, Np, HB0;
};

__global__ void prep_hist(PrepHist a) {
    int b = blockIdx.x, t = threadIdx.x;
    if (b >= a.HB0) {
        int base = (b - a.HB0) * 2048 + t;
        int E = a.Ew + a.Ec;
        int dd[8];
        bool val[8];
#pragma unroll
        for (int j = 0; j < 8; ++j) {
            int i = base + j * 256;
            val[j] = i < E;
            dd[j] = 0;
            if (val[j]) dd[j] = (i < a.Ew) ? a.dst_w[i] : (a.Np + a.dst_c[i - a.Ew]);
        }
        int rk[8];
#pragma unroll
        for (int j = 0; j < 8; ++j)
            if (val[j]) rk[j] = atomicAdd(&a.deg[dd[j]], 1);
#pragma unroll
        for (int j = 0; j < 8; ++j)
            if (val[j]) a.rank[base + j * 256] = rk[j];
        return;
    }
    if (b == 56) {
        if (t < 128) {
            a.bsum[t] = a.bw[t] + a.bc[t];
            float acc = a.b2a[t];
            for (int k = 0; k < DHID; ++k) acc += a.gnb_a[k] * a.W2a[k * DHID + t];
            a.row_a[t] = acc;
            a.colsum[t] = 0.f;
            a.colsumsq[t] = 0.f;
            a.xs_w_ph[t] = 0;            // phantom msg = 0
            a.xs_c_ph[t] = 0;
        } else if (t < 136) {
            *reinterpret_cast<float*>(a.xs_w_ph + 128 + 2 * (t - 128)) = -1e30f;
        } else if (t < 144) {
            *reinterpret_cast<float*>(a.xs_c_ph + 128 + 2 * (t - 136)) = -1e30f;
        }
        return;
    }
    int j = b >> 3;
    int idx = (b & 7) * 256 + t;
    int lane = idx & 63, kk = (idx >> 6) & 3, nt = idx >> 8;
    int col = nt * 16 + (lane & 15);
    int k0 = kk * 32 + ((lane >> 4) << 3);
    if (j < 5) {
        const float* W = j == 0 ? a.Wlp : j == 1 ? a.Wsc : j == 2 ? a.Wla : j == 3 ? a.Wsw : a.W2p;
        unsigned short* out = j == 0 ? a.WlinP_p : j == 1 ? a.WsrcP_c : j == 2 ? a.WlinP_a
                              : j == 3 ? a.WsrcP_w : a.W2P_p;
        for (int i = 0; i < 8; ++i) out[idx * 8 + i] = f2bf(W[(k0 + i) * DHID + col]);
    } else if (j == 5) {
        if (idx >= 2 * 256) return;
        const float *W = nullptr, *A = nullptr;
        int h = col & 7;
        if (col < 24) {
            int which = col >> 3;
            W = which == 0 ? a.Wdw : which == 1 ? a.Wsc : a.Wdc;
            A = which == 0 ? a.adw : which == 1 ? a.asc_ : a.adc_;
        }
        for (int i = 0; i < 8; ++i) {
            float v = 0.f;
            if (W)
                for (int c = 0; c < 16; ++c) v += W[(k0 + i) * DHID + h * 16 + c] * A[h * 16 + c];
            a.VscP_p[idx * 8 + i] = f2bf(v);
        }
    } else {
        if (idx >= 256) return;
        int h = col & 7;
        for (int i = 0; i < 8; ++i) {
            float v = 0.f;
            if (col < 8)
                for (int c = 0; c < 16; ++c)
                    v += a.Wsw[(k0 + i) * DHID + h * 16 + c] * a.asw_[h * 16 + c];
            a.VscP_a[idx * 8 + i] = f2bf(v);
        }
    }
}

// ---------------------------------------------------------------------------
// Exclusive scan pass 1 (per-block) with pad-to-4; bsums collects block totals.
// ---------------------------------------------------------------------------
__global__ void scan1(const int* __restrict__ in, int n, int* __restrict__ out,
                      int* __restrict__ bsums) {
    __shared__ int sh[SCAN_T];
    int t = threadIdx.x;
    long base = (long)blockIdx.x * SCAN_T * SCAN_I;
    int v[SCAN_I];
    int s = 0;
#pragma unroll
    for (int j = 0; j < SCAN_I; ++j) {
        long idx = base + (long)t * SCAN_I + j;
        int x = (idx < n) ? in[idx] : 0;
        x = (x + 3) & ~3;
        v[j] = x;
        s += x;
    }
    sh[t] = s;
    __syncthreads();
    for (int off = 1; off < SCAN_T; off <<= 1) {
        int x = (t >= off) ? sh[t - off] : 0;
        __syncthreads();
        sh[t] += x;
        __syncthreads();
    }
    int run = sh[t] - s;
#pragma unroll
    for (int j = 0; j < SCAN_I; ++j) {
        long idx = base + (long)t * SCAN_I + j;
        if (idx < n) out[idx] = run;
        run += v[j];
    }
    if (t == SCAN_T - 1) bsums[blockIdx.x] = sh[SCAN_T - 1];
}

// ---------------------------------------------------------------------------
// scan3_tails: scans bs1 (nb <= 256) in-LDS; off2 = off_raw + prefix; writes
// sentinel off2[n2]; writes only the phantom TAIL slots of each padded segment.
// ---------------------------------------------------------------------------
__global__ void scan3_tails(const int* __restrict__ off_raw, const int* __restrict__ bs1,
                            int nb, int n2, int* __restrict__ off2,
                            const int* __restrict__ deg,
                            int Np, int Na, int* __restrict__ srcu) {
    __shared__ int pf[SCAN_T];
    int t = threadIdx.x;
    pf[t] = (t < nb) ? bs1[t] : 0;
    __syncthreads();
    for (int off = 1; off < SCAN_T; off <<= 1) {
        int x = (t >= off) ? pf[t - off] : 0;
        __syncthreads();
        pf[t] += x;
        __syncthreads();
    }
    int i = blockIdx.x * 256 + t;
    if (i < n2) {
        int g = i >> 10;
        int o = off_raw[i] + (g ? pf[g - 1] : 0);
        off2[i] = o;
        int dgi = deg[i];
        int padded = (dgi + 3) & ~3;
        int ph = (i < Np) ? Na : Np;
        for (int k = dgi; k < padded; ++k) srcu[o + k] = ph;
    }
    if (blockIdx.x == 0 && t == 0) off2[n2] = pf[nb - 1];
}

// ---------------------------------------------------------------------------
// MFMA projection body (two-barrier, coalesced block-wide staging).
// xs rows: [128 bf16 msg][8 f32 src-side scores]. a_d arrays stay separate.
// ---------------------------------------------------------------------------
template <int NSC>
__device__ void proj_body(unsigned short* xt, int bid,
                          const float* __restrict__ x, int nrows,
                          const unsigned short* __restrict__ WlinP, const float* __restrict__ blin,
                          const unsigned short* __restrict__ WsrcP,
                          const unsigned short* __restrict__ VscP,
                          unsigned short* __restrict__ xs,
                          float* __restrict__ ad0, float* __restrict__ ad1) {
    int t = threadIdx.x;
    int lane = t & 63, w = t >> 6;
    long row0 = (long)bid * BM;
    for (int it = 0; it < 16; ++it) {
        int idx2 = t + it * 256;
        int r = idx2 >> 6, cp = idx2 & 63;
        long gr = row0 + r;
        float v0 = 0.f, v1 = 0.f;
        if (gr < nrows) { v0 = x[gr * DHID + 2 * cp]; v1 = x[gr * DHID + 2 * cp + 1]; }
        *reinterpret_cast<uint32_t*>(&xt[r * LDST + 2 * cp]) = pack2bf(v0, v1);
    }
    __syncthreads();
    int arow = w * 16 + (lane & 15);
    int koff = (lane >> 4) << 3;
    short8 af[4];
#pragma unroll
    for (int kk = 0; kk < 4; ++kk)
        af[kk] = *reinterpret_cast<const short8*>(&xt[arow * LDST + kk * 32 + koff]);
    const short8* Bl = reinterpret_cast<const short8*>(WlinP);
    f32x4 acc[8];
#pragma unroll
    for (int nt = 0; nt < 8; ++nt) {
        f32x4 a = {0.f, 0.f, 0.f, 0.f};
#pragma unroll
        for (int kk = 0; kk < 4; ++kk)
            a = __builtin_amdgcn_mfma_f32_16x16x32_bf16(af[kk], Bl[(nt * 4 + kk) * 64 + lane], a, 0, 0, 0);
        acc[nt] = a;
    }
    __syncthreads();
    int orow = w * 16 + ((lane >> 4) << 2);
    int ccol = lane & 15;
#pragma unroll
    for (int nt = 0; nt < 8; ++nt) {
        float b = blin[nt * 16 + ccol];
#pragma unroll
        for (int r = 0; r < 4; ++r) {
            float e = fmaxf(acc[nt][r] + b, 0.f);
            xt[(orow + r) * LDST + nt * 16 + ccol] = f2bf(e);
        }
    }
    __syncthreads();
#pragma unroll
    for (int kk = 0; kk < 4; ++kk)
        af[kk] = *reinterpret_cast<const short8*>(&xt[arow * LDST + kk * 32 + koff]);
    const short8* Bs = reinterpret_cast<const short8*>(WsrcP);
#pragma unroll
    for (int nt = 0; nt < 8; ++nt) {
        f32x4 a = {0.f, 0.f, 0.f, 0.f};
#pragma unroll
        for (int kk = 0; kk < 4; ++kk)
            a = __builtin_amdgcn_mfma_f32_16x16x32_bf16(af[kk], Bs[(nt * 4 + kk) * 64 + lane], a, 0, 0, 0);
        acc[nt] = a;
    }
    const short8* Bv = reinterpret_cast<const short8*>(VscP);
    f32x4 sacc0 = {0.f, 0.f, 0.f, 0.f}, sacc1 = {0.f, 0.f, 0.f, 0.f};
#pragma unroll
    for (int kk = 0; kk < 4; ++kk)
        sacc0 = __builtin_amdgcn_mfma_f32_16x16x32_bf16(af[kk], Bv[kk * 64 + lane], sacc0, 0, 0, 0);
    if (NSC > 1) {
#pragma unroll
        for (int kk = 0; kk < 4; ++kk)
            sacc1 = __builtin_amdgcn_mfma_f32_16x16x32_bf16(af[kk], Bv[(4 + kk) * 64 + lane], sacc1, 0, 0, 0);
    }
#pragma unroll
    for (int nt = 0; nt < 8; ++nt) {
#pragma unroll
        for (int r = 0; r < 4; ++r) {
            long gr = row0 + orow + r;
            if (gr < nrows) xs[gr * XST + nt * 16 + ccol] = f2bf(acc[nt][r]);
        }
    }
#pragma unroll
    for (int st = 0; st < NSC; ++st) {
        int scol = st * 16 + ccol;
        int h = scol & 7, which = scol >> 3;
        f32x4 s = (st == 0) ? sacc0 : sacc1;
#pragma unroll
        for (int r = 0; r < 4; ++r) {
            long gr = row0 + orow + r;
            if (gr >= nrows) continue;
            if (NSC == 2) {
                if (which == 0) ad0[gr * H + h] = s[r];
                else if (which == 1)
                    *reinterpret_cast<float*>(xs + gr * XST + 128 + 2 * h) = s[r];
                else if (which == 2) ad1[gr * H + h] = s[r];
                // which == 3: zero padding column — skip
            } else {
                if (which == 0)
                    *reinterpret_cast<float*>(xs + gr * XST + 128 + 2 * h) = s[r];
                // which == 1: zero padding column — skip
            }
        }
    }
}

// ---------------------------------------------------------------------------
// K4 MEGA: proj_paper, proj_author, then atomic-free scatter (MLP-4).
// ---------------------------------------------------------------------------
struct MegaArgs {
    const float* x_p; int Np;
    const unsigned short* WlinP_p; const float* blp;
    const unsigned short* WsrcP_c; const unsigned short* VscP_p;
    unsigned short* xs_c; float *a_d_w, *a_d_c;
    const float* x_a; int Na;
    const unsigned short* WlinP_a; const float* bla;
    const unsigned short* WsrcP_w; const unsigned short* VscP_a;
    unsigned short* xs_w;
    const int *src_w, *dst_w, *src_c, *dst_c;
    int Ew, Ec;
    const int *off2, *rank;
    int* srcu;
    int PB, AB;
};

__global__ __launch_bounds__(256) void mega(MegaArgs a) {
    __shared__ unsigned short xt[BM * LDST];
    int b = blockIdx.x;
    if (b < a.PB) {
        proj_body<2>(xt, b, a.x_p, a.Np, a.WlinP_p, a.blp, a.WsrcP_c, a.VscP_p,
                     a.xs_c, a.a_d_w, a.a_d_c);
        return;
    }
    if (b < a.PB + a.AB) {
        proj_body<1>(xt, b - a.PB, a.x_a, a.Na, a.WlinP_a, a.bla, a.WsrcP_w, a.VscP_a,
                     a.xs_w, nullptr, nullptr);
        return;
    }
    int base = (b - a.PB - a.AB) * 1024 + threadIdx.x;
    int E = a.Ew + a.Ec;
    int s[4], di[4], rk[4];
    bool val[4];
#pragma unroll
    for (int j = 0; j < 4; ++j) {
        int i = base + j * 256;
        val[j] = i < E;
        s[j] = di[j] = rk[j] = 0;
        if (val[j]) {
            if (i < a.Ew) { s[j] = a.src_w[i]; di[j] = a.dst_w[i]; }
            else { int q = i - a.Ew; s[j] = a.src_c[q]; di[j] = a.Np + a.dst_c[q]; }
            rk[j] = a.rank[i];
        }
    }
    int pos[4];
#pragma unroll
    for (int j = 0; j < 4; ++j)
        if (val[j]) pos[j] = a.off2[di[j]] + rk[j];
#pragma unroll
    for (int j = 0; j < 4; ++j)
        if (val[j]) a.srcu[pos[j]] = s[j];
}

// ---------------------------------------------------------------------------
// Gather ∥ author fill, WORK-STEALING persistent blocks (chunked counter:
// one atomic grab = 4 groups = 16 consecutive papers). Stats fused in-register,
// block-level LDS reduce + 128x2 atomics at the end.
// ---------------------------------------------------------------------------
#define FILLB 391
#define GATB 2048
#define WCHUNK 4
__global__ __launch_bounds__(256) void gat_gather(
    const int* __restrict__ off, const int* __restrict__ srcu,
    const float* __restrict__ a_d_w, const float* __restrict__ a_d_c,
    const unsigned short* __restrict__ xs_w, const unsigned short* __restrict__ xs_c,
    uint32_t* __restrict__ gatb, int Np, int nselfw, int ngroups,
    int* __restrict__ wcnt,
    float* __restrict__ colsum, float* __restrict__ colsumsq,
    const float* __restrict__ row_a, float4* __restrict__ outa, long n4) {
    if (blockIdx.x < FILLB) {
        long i = (long)blockIdx.x * 256 + threadIdx.x;
        long stride = (long)FILLB * 256;
        const float4* r4 = reinterpret_cast<const float4*>(row_a);
        for (; i < n4; i += stride) outa[i] = r4[i & 31];
        return;
    }
    __shared__ float red1[4 * DHID], red2[4 * DHID];
    __shared__ int sh_base;
    int t = threadIdx.x;
    int l = t & 63;
    int rg = t >> 6;
    int h = l >> 3;
    int sco = 128 + 2 * h;
    float cs0 = 0.f, cs1 = 0.f, cq0 = 0.f, cq1 = 0.f;
    while (true) {
        __syncthreads();
        if (t == 0) sh_base = atomicAdd(wcnt, 1) * WCHUNK;
        __syncthreads();
        int bg = sh_base;
        if (bg >= ngroups) break;
        for (int gi = 0; gi < WCHUNK; ++gi) {
            int g = bg + gi;
            if (g >= ngroups) break;
            int d = g * 4 + rg;
            if (d >= Np) continue;
            int iw = off[d], w1 = off[d + 1];
            int ic = off[Np + d], c1 = off[Np + d + 1];
            float adw = a_d_w[(long)d * H + h];
            float adc = a_d_c[(long)d * H + h];
            float denw = 0.f, n0w = 0.f, n1w = 0.f;
            float denc = 0.f, n0c = 0.f, n1c = 0.f;
            if (d < nselfw) {
                const unsigned short* r = xs_w + (long)d * XST;
                float e = *reinterpret_cast<const float*>(r + sco) + adw;
                e = e > 0.f ? e : NEG_SLOPE * e;
                float p = __expf(e);
                uint32_t v = *reinterpret_cast<const uint32_t*>(r + 2 * l);
                denw += p; n0w += p * bflo(v); n1w += p * bfhi(v);
            }
            {
                const unsigned short* r = xs_c + (long)d * XST;
                float e = *reinterpret_cast<const float*>(r + sco) + adc;
                e = e > 0.f ? e : NEG_SLOPE * e;
                float p = __expf(e);
                uint32_t v = *reinterpret_cast<const uint32_t*>(r + 2 * l);
                denc += p; n0c += p * bflo(v); n1c += p * bfhi(v);
            }
            while (iw < w1 || ic < c1) {
                bool hw = iw < w1, hc = ic < c1;
                int4 sw, sc;
                if (hw) sw = *reinterpret_cast<const int4*>(srcu + iw);
                if (hc) sc = *reinterpret_cast<const int4*>(srcu + ic);
                float ew[4], ec[4];
                uint32_t vw[4], vc[4];
                if (hw) {
                    const unsigned short* r0 = xs_w + (long)sw.x * XST;
                    const unsigned short* r1 = xs_w + (long)sw.y * XST;
                    const unsigned short* r2 = xs_w + (long)sw.z * XST;
                    const unsigned short* r3 = xs_w + (long)sw.w * XST;
                    ew[0] = *reinterpret_cast<const float*>(r0 + sco);
                    ew[1] = *reinterpret_cast<const float*>(r1 + sco);
                    ew[2] = *reinterpret_cast<const float*>(r2 + sco);
                    ew[3] = *reinterpret_cast<const float*>(r3 + sco);
                    vw[0] = *reinterpret_cast<const uint32_t*>(r0 + 2 * l);
                    vw[1] = *reinterpret_cast<const uint32_t*>(r1 + 2 * l);
                    vw[2] = *reinterpret_cast<const uint32_t*>(r2 + 2 * l);
                    vw[3] = *reinterpret_cast<const uint32_t*>(r3 + 2 * l);
                }
                if (hc) {
                    const unsigned short* r0 = xs_c + (long)sc.x * XST;
                    const unsigned short* r1 = xs_c + (long)sc.y * XST;
                    const unsigned short* r2 = xs_c + (long)sc.z * XST;
                    const unsigned short* r3 = xs_c + (long)sc.w * XST;
                    ec[0] = *reinterpret_cast<const float*>(r0 + sco);
                    ec[1] = *reinterpret_cast<const float*>(r1 + sco);
                    ec[2] = *reinterpret_cast<const float*>(r2 + sco);
                    ec[3] = *reinterpret_cast<const float*>(r3 + sco);
                    vc[0] = *reinterpret_cast<const uint32_t*>(r0 + 2 * l);
                    vc[1] = *reinterpret_cast<const uint32_t*>(r1 + 2 * l);
                    vc[2] = *reinterpret_cast<const uint32_t*>(r2 + 2 * l);
                    vc[3] = *reinterpret_cast<const uint32_t*>(r3 + 2 * l);
                }
                if (hw) {
#pragma unroll
                    for (int j = 0; j < 4; ++j) {
                        float e = ew[j] + adw;
                        e = e > 0.f ? e : NEG_SLOPE * e;
                        float p = __expf(e);
                        denw += p;
                        n0w += p * bflo(vw[j]);
                        n1w += p * bfhi(vw[j]);
                    }
                    iw += 4;
                }
                if (hc) {
#pragma unroll
                    for (int j = 0; j < 4; ++j) {
                        float e = ec[j] + adc;
                        e = e > 0.f ? e : NEG_SLOPE * e;
                        float p = __expf(e);
                        denc += p;
                        n0c += p * bflo(vc[j]);
                        n1c += p * bfhi(vc[j]);
                    }
                    ic += 4;
                }
            }
            float rw = 1.f / (denw + 1e-16f);
            float rc = 1.f / (denc + 1e-16f);
            float o0 = n0w * rw + n0c * rc;
            float o1 = n1w * rw + n1c * rc;
            gatb[(long)d * 64 + l] = pack2bf(o0, o1);
            cs0 += o0; cs1 += o1;
            cq0 += o0 * o0; cq1 += o1 * o1;
        }
    }
    red1[rg * DHID + 2 * l] = cs0;
    red1[rg * DHID + 2 * l + 1] = cs1;
    red2[rg * DHID + 2 * l] = cq0;
    red2[rg * DHID + 2 * l + 1] = cq1;
    __syncthreads();
    if (t < DHID) {
        float s1 = red1[t] + red1[DHID + t] + red1[2 * DHID + t] + red1[3 * DHID + t];
        float s2 = red2[t] + red2[DHID + t] + red2[2 * DHID + t] + red2[3 * DHID + t];
        atomAddF(colsum + t, s1);
        atomAddF(colsumsq + t, s2);
    }
}

// ---------------------------------------------------------------------------
// K6: final_mfma — stats from raw Σgat, Σgat² with analytic bsum correction:
//   mu = Σg/Np + b;  E[x²] = Σg²/Np + 2b·Σg/Np + b²;  var = E[x²] − mu²·ms(2−ms)
// ---------------------------------------------------------------------------
__global__ __launch_bounds__(256) void final_fill(
    const uint32_t* __restrict__ gatb, const float* __restrict__ bsum,
    const float* __restrict__ colsum, const float* __restrict__ colsumsq,
    const float* __restrict__ gnw, const float* __restrict__ gnb,
    const float* __restrict__ gnm,
    const unsigned short* __restrict__ W2P, const float* __restrict__ b2,
    float* __restrict__ out, int Np) {
    __shared__ unsigned short xt[BM * LDST];
    __shared__ float cscale[DHID], cshift[DHID];
    int b = blockIdx.x;
    int t = threadIdx.x;
    int lane = t & 63, w = t >> 6;
    long row0 = (long)b * BM;
    if (t < DHID) {
        float invN = 1.f / (float)Np;
        float bb = bsum[t];
        float sg = colsum[t] * invN;           // E[gat]
        float eq = colsumsq[t] * invN;         // E[gat^2]
        float mu = sg + bb;
        float ex2 = eq + 2.f * bb * sg + bb * bb;
        float ms = gnm[t];
        float var = ex2 - mu * mu * ms * (2.f - ms);
        float sc = gnw[t] * rsqrtf(var + GN_EPS);
        cscale[t] = sc;
        cshift[t] = (bb - ms * mu) * sc + gnb[t];
    }
    __syncthreads();
    int wrow0 = w * 16;
    float cs0 = cscale[2 * lane], cf0 = cshift[2 * lane];
    float cs1 = cscale[2 * lane + 1], cf1 = cshift[2 * lane + 1];
    for (int it = 0; it < 16; ++it) {
        int r = wrow0 + it;
        long gr = row0 + r;
        float v0 = 0.f, v1 = 0.f;
        if (gr < Np) {
            uint32_t u = gatb[gr * 64 + lane];
            v0 = bflo(u) * cs0 + cf0;
            v1 = bfhi(u) * cs1 + cf1;
        }
        *reinterpret_cast<uint32_t*>(&xt[r * LDST + 2 * lane]) = pack2bf(v0, v1);
    }
    int arow = wrow0 + (lane & 15);
    int koff = (lane >> 4) << 3;
    short8 af[4];
#pragma unroll
    for (int kk = 0; kk < 4; ++kk)
        af[kk] = *reinterpret_cast<const short8*>(&xt[arow * LDST + kk * 32 + koff]);
    const short8* Bw = reinterpret_cast<const short8*>(W2P);
    int orow = wrow0 + ((lane >> 4) << 2);
    int ccol = lane & 15;
#pragma unroll
    for (int nt = 0; nt < 8; ++nt) {
        f32x4 a = {0.f, 0.f, 0.f, 0.f};
#pragma unroll
        for (int kk = 0; kk < 4; ++kk)
            a = __builtin_amdgcn_mfma_f32_16x16x32_bf16(af[kk], Bw[(nt * 4 + kk) * 64 + lane], a, 0, 0, 0);
        float bb = b2[nt * 16 + ccol];
#pragma unroll
        for (int r = 0; r < 4; ++r) {
            long gr = row0 + orow + r;
            if (gr < Np) out[gr * DHID + nt * 16 + ccol] = a[r] + bb;
        }
    }
}

// ---------------------------------------------------------------------------
extern "C" void kernel_launch(void* const* d_in, const int* in_sizes, int n_in,
                              void* d_out, int out_size, void* d_ws, size_t ws_size,
                              hipStream_t stream) {
    const float* x_p   = (const float*)d_in[0];
    const float* x_a   = (const float*)d_in[1];
    const int*   e_w   = (const int*)d_in[2];
    const int*   e_c   = (const int*)d_in[3];
    const float* Wlp   = (const float*)d_in[4];
    const float* blp   = (const float*)d_in[5];
    const float* Wla   = (const float*)d_in[6];
    const float* bla   = (const float*)d_in[7];
    const float* Wsw   = (const float*)d_in[8];
    const float* Wdw   = (const float*)d_in[9];
    const float* asw   = (const float*)d_in[10];
    const float* adw   = (const float*)d_in[11];
    const float* bw    = (const float*)d_in[12];
    const float* Wsc   = (const float*)d_in[13];
    const float* Wdc   = (const float*)d_in[14];
    const float* asc   = (const float*)d_in[15];
    const float* adc   = (const float*)d_in[16];
    const float* bc    = (const float*)d_in[17];
    const float* gnw_p = (const float*)d_in[18];
    const float* gnb_p = (const float*)d_in[19];
    const float* gnm_p = (const float*)d_in[20];
    const float* gnb_a = (const float*)d_in[22];
    const float* W2p   = (const float*)d_in[24];
    const float* b2p   = (const float*)d_in[25];
    const float* W2a   = (const float*)d_in[26];
    const float* b2a   = (const float*)d_in[27];

    int Np = in_sizes[0] / DHID;
    int Na = in_sizes[1] / DHID;
    int Ew = in_sizes[2] / 2;
    int Ec = in_sizes[3] / 2;
    int nself_w = Na < Np ? Na : Np;
    int tot_edges = Ew + Ec;
    int maxTot = tot_edges + 6 * Np + 8;

    float* ws = (float*)d_ws;
    uint32_t* gatb = (uint32_t*)ws;                    // Np*64 (bf16 pairs)
    float* a_d_w = (float*)(gatb + (size_t)Np * 64);   // Np*8
    float* a_d_c = a_d_w + (size_t)Np * H;             // Np*8
    float* bsum  = a_d_c + (size_t)Np * H;             // 128
    float* row_a = bsum + DHID;                        // 128
    float* colsum   = row_a + DHID;                    // 128
    float* colsumsq = colsum + DHID;                   // 128
    int*   deg   = (int*)(colsumsq + DHID);            // 2*Np (memset w/ wcnt)
    int*   wcnt  = deg + 2 * Np;                       // 1   (work-steal counter)
    int* off_raw = wcnt + 1;                           // 2*Np
    int* off2    = off_raw + 2 * Np;                   // 2*Np + 1
    int* bs1     = off2 + 2 * Np + 1;                  // 512
    uintptr_t up = (uintptr_t)(bs1 + 512);
    up = (up + 15) & ~(uintptr_t)15;
    int* srcu = (int*)up;                              // maxTot
    int* rank = srcu + maxTot;                         // tot_edges
    unsigned short* xs_w = (unsigned short*)(rank + tot_edges);  // (Na+1)*XST
    unsigned short* xs_c = xs_w + (size_t)(Na + 1) * XST;        // (Np+1)*XST
    up = (uintptr_t)(xs_c + (size_t)(Np + 1) * XST);
    up = (up + 15) & ~(uintptr_t)15;
    unsigned short* WlinP_p = (unsigned short*)up;
    unsigned short* WsrcP_c = WlinP_p + 16384;
    unsigned short* WlinP_a = WsrcP_c + 16384;
    unsigned short* WsrcP_w = WlinP_a + 16384;
    unsigned short* W2P_p   = WsrcP_w + 16384;
    unsigned short* VscP_p  = W2P_p + 16384;
    unsigned short* VscP_a  = VscP_p + 4096;

    hipMemsetAsync(deg, 0, (2 * (size_t)Np + 1) * sizeof(int), stream);

    int HB = (tot_edges + 2047) / 2048;      // MLP-8: 8 edges/thread
    {
        PrepHist pa;
        pa.Wlp = Wlp; pa.Wsc = Wsc; pa.Wla = Wla; pa.Wsw = Wsw; pa.W2p = W2p;
        pa.Wdw = Wdw; pa.adw = adw; pa.asc_ = asc; pa.Wdc = Wdc; pa.adc_ = adc; pa.asw_ = asw;
        pa.WlinP_p = WlinP_p; pa.WsrcP_c = WsrcP_c; pa.WlinP_a = WlinP_a;
        pa.WsrcP_w = WsrcP_w; pa.W2P_p = W2P_p; pa.VscP_p = VscP_p; pa.VscP_a = VscP_a;
        pa.bw = bw; pa.bc = bc; pa.gnb_a = gnb_a; pa.W2a = W2a; pa.b2a = b2a;
        pa.bsum = bsum; pa.row_a = row_a; pa.colsum = colsum; pa.colsumsq = colsumsq;
        pa.xs_w_ph = xs_w + (size_t)Na * XST;
        pa.xs_c_ph = xs_c + (size_t)Np * XST;
        pa.dst_w = e_w + Ew; pa.dst_c = e_c + Ec;
        pa.deg = deg; pa.rank = rank;
        pa.Ew = Ew; pa.Ec = Ec;
        pa.Np = Np; pa.HB0 = 57;
        prep_hist<<<57 + HB, 256, 0, stream>>>(pa);
    }

    int n2 = 2 * Np;
    int nb = (n2 + SCAN_T * SCAN_I - 1) / (SCAN_T * SCAN_I);   // must be <= 256
    scan1<<<nb, SCAN_T, 0, stream>>>(deg, n2, off_raw, bs1);

    scan3_tails<<<(n2 + 255) / 256, 256, 0, stream>>>(
        off_raw, bs1, nb, n2, off2, deg, Np, Na, srcu);

    {
        MegaArgs ma;
        ma.x_p = x_p; ma.Np = Np; ma.WlinP_p = WlinP_p; ma.blp = blp;
        ma.WsrcP_c = WsrcP_c; ma.VscP_p = VscP_p;
        ma.xs_c = xs_c; ma.a_d_w = a_d_w; ma.a_d_c = a_d_c;
        ma.x_a = x_a; ma.Na = Na; ma.WlinP_a = WlinP_a; ma.bla = bla;
        ma.WsrcP_w = WsrcP_w; ma.VscP_a = VscP_a;
        ma.xs_w = xs_w;
        ma.src_w = e_w; ma.dst_w = e_w + Ew; ma.src_c = e_c; ma.dst_c = e_c + Ec;
        ma.Ew = Ew; ma.Ec = Ec;
        ma.off2 = off2; ma.rank = rank; ma.srcu = srcu;
        ma.PB = (Np + BM - 1) / BM;
        ma.AB = (Na + BM - 1) / BM;
        int SB = (tot_edges + 1023) / 1024;
        mega<<<ma.PB + ma.AB + SB, 256, 0, stream>>>(ma);
    }

    {
        long n4 = (long)Na * DHID / 4;
        int ngroups = (Np + 3) / 4;
        int GB = ngroups < GATB ? ngroups : GATB;
        gat_gather<<<FILLB + GB, 256, 0, stream>>>(
            off2, srcu, a_d_w, a_d_c, xs_w, xs_c, gatb, Np, nself_w, ngroups,
            wcnt, colsum, colsumsq,
            row_a, (float4*)((float*)d_out + (size_t)Np * DHID), n4);
    }

    final_fill<<<(Np + BM - 1) / BM, 256, 0, stream>>>(
        gatb, bsum, colsum, colsumsq, gnw_p, gnb_p, gnm_p, W2P_p, b2p,
        (float*)d_out, Np);
}

// Round 17
// 255.186 us; speedup vs baseline: 1.1747x; 1.1747x over previous
//
#include <hip/hip_runtime.h>
#include <cstdint>
#include <cstddef>

#define H 8
#define DHID 128
#define XST 144          // xs row stride in shorts: 128 bf16 msg + 8 f32 scores (288B)
#define BM 64            // rows per MFMA block
#define LDST 136         // padded LDS row stride (bf16 elems)
#define NEG_SLOPE 0.2f
#define GN_EPS 1e-5f

#define SCAN_T 256
#define SCAN_I 4         // 1024 elements per scan block; requires 2*Np <= 256*1024

typedef __attribute__((ext_vector_type(8))) short short8;
typedef __attribute__((ext_vector_type(4))) float f32x4;

__device__ __forceinline__ void atomAddF(float* p, float v) {
    __hip_atomic_fetch_add(p, v, __ATOMIC_RELAXED, __HIP_MEMORY_SCOPE_AGENT);
}
__device__ __forceinline__ unsigned short f2bf(float f) {
    uint32_t u = __float_as_uint(f);
    uint32_t r = (u + 0x7FFFu + ((u >> 16) & 1u)) >> 16;
    return (unsigned short)r;
}
__device__ __forceinline__ uint32_t pack2bf(float lo, float hi) {
    return (uint32_t)f2bf(lo) | ((uint32_t)f2bf(hi) << 16);
}
__device__ __forceinline__ float bflo(uint32_t v) { return __uint_as_float(v << 16); }
__device__ __forceinline__ float bfhi(uint32_t v) { return __uint_as_float(v & 0xFFFF0000u); }

// ---------------------------------------------------------------------------
// K1: prep (pack weights -> MFMA B-frags, attention fold inline, misc init)
//     ∥ deg_hist (real edges; MLP-8; records per-edge rank).
// ---------------------------------------------------------------------------
struct PrepHist {
    const float *Wlp, *Wsc, *Wla, *Wsw, *W2p;
    const float *Wdw, *adw, *asc_, *Wdc, *adc_, *asw_;
    unsigned short *WlinP_p, *WsrcP_c, *WlinP_a, *WsrcP_w, *W2P_p, *VscP_p, *VscP_a;
    const float *bw, *bc, *gnb_a, *W2a, *b2a;
    float *bsum, *row_a, *colsum, *colsumsq;
    unsigned short *xs_w_ph, *xs_c_ph;   // phantom row bases
    const int *dst_w, *dst_c;
    int *deg, *rank;
    int Ew, Ec, Np, HB0;
};

__global__ void prep_hist(PrepHist a) {
    int b = blockIdx.x, t = threadIdx.x;
    if (b >= a.HB0) {
        int base = (b - a.HB0) * 2048 + t;
        int E = a.Ew + a.Ec;
        int dd[8];
        bool val[8];
#pragma unroll
        for (int j = 0; j < 8; ++j) {
            int i = base + j * 256;
            val[j] = i < E;
            dd[j] = 0;
            if (val[j]) dd[j] = (i < a.Ew) ? a.dst_w[i] : (a.Np + a.dst_c[i - a.Ew]);
        }
        int rk[8];
#pragma unroll
        for (int j = 0; j < 8; ++j)
            if (val[j]) rk[j] = atomicAdd(&a.deg[dd[j]], 1);
#pragma unroll
        for (int j = 0; j < 8; ++j)
            if (val[j]) a.rank[base + j * 256] = rk[j];
        return;
    }
    if (b == 56) {
        if (t < 128) {
            a.bsum[t] = a.bw[t] + a.bc[t];
            float acc = a.b2a[t];
            for (int k = 0; k < DHID; ++k) acc += a.gnb_a[k] * a.W2a[k * DHID + t];
            a.row_a[t] = acc;
            a.colsum[t] = 0.f;
            a.colsumsq[t] = 0.f;
            a.xs_w_ph[t] = 0;            // phantom msg = 0
            a.xs_c_ph[t] = 0;
        } else if (t < 136) {
            *reinterpret_cast<float*>(a.xs_w_ph + 128 + 2 * (t - 128)) = -1e30f;
        } else if (t < 144) {
            *reinterpret_cast<float*>(a.xs_c_ph + 128 + 2 * (t - 136)) = -1e30f;
        }
        return;
    }
    int j = b >> 3;
    int idx = (b & 7) * 256 + t;
    int lane = idx & 63, kk = (idx >> 6) & 3, nt = idx >> 8;
    int col = nt * 16 + (lane & 15);
    int k0 = kk * 32 + ((lane >> 4) << 3);
    if (j < 5) {
        const float* W = j == 0 ? a.Wlp : j == 1 ? a.Wsc : j == 2 ? a.Wla : j == 3 ? a.Wsw : a.W2p;
        unsigned short* out = j == 0 ? a.WlinP_p : j == 1 ? a.WsrcP_c : j == 2 ? a.WlinP_a
                              : j == 3 ? a.WsrcP_w : a.W2P_p;
        for (int i = 0; i < 8; ++i) out[idx * 8 + i] = f2bf(W[(k0 + i) * DHID + col]);
    } else if (j == 5) {
        if (idx >= 2 * 256) return;
        const float *W = nullptr, *A = nullptr;
        int h = col & 7;
        if (col < 24) {
            int which = col >> 3;
            W = which == 0 ? a.Wdw : which == 1 ? a.Wsc : a.Wdc;
            A = which == 0 ? a.adw : which == 1 ? a.asc_ : a.adc_;
        }
        for (int i = 0; i < 8; ++i) {
            float v = 0.f;
            if (W)
                for (int c = 0; c < 16; ++c) v += W[(k0 + i) * DHID + h * 16 + c] * A[h * 16 + c];
            a.VscP_p[idx * 8 + i] = f2bf(v);
        }
    } else {
        if (idx >= 256) return;
        int h = col & 7;
        for (int i = 0; i < 8; ++i) {
            float v = 0.f;
            if (col < 8)
                for (int c = 0; c < 16; ++c)
                    v += a.Wsw[(k0 + i) * DHID + h * 16 + c] * a.asw_[h * 16 + c];
            a.VscP_a[idx * 8 + i] = f2bf(v);
        }
    }
}

// ---------------------------------------------------------------------------
// Exclusive scan pass 1 (per-block) with pad-to-4; bsums collects block totals.
// ---------------------------------------------------------------------------
__global__ void scan1(const int* __restrict__ in, int n, int* __restrict__ out,
                      int* __restrict__ bsums) {
    __shared__ int sh[SCAN_T];
    int t = threadIdx.x;
    long base = (long)blockIdx.x * SCAN_T * SCAN_I;
    int v[SCAN_I];
    int s = 0;
#pragma unroll
    for (int j = 0; j < SCAN_I; ++j) {
        long idx = base + (long)t * SCAN_I + j;
        int x = (idx < n) ? in[idx] : 0;
        x = (x + 3) & ~3;
        v[j] = x;
        s += x;
    }
    sh[t] = s;
    __syncthreads();
    for (int off = 1; off < SCAN_T; off <<= 1) {
        int x = (t >= off) ? sh[t - off] : 0;
        __syncthreads();
        sh[t] += x;
        __syncthreads();
    }
    int run = sh[t] - s;
#pragma unroll
    for (int j = 0; j < SCAN_I; ++j) {
        long idx = base + (long)t * SCAN_I + j;
        if (idx < n) out[idx] = run;
        run += v[j];
    }
    if (t == SCAN_T - 1) bsums[blockIdx.x] = sh[SCAN_T - 1];
}

// ---------------------------------------------------------------------------
// scan3_tails: scans bs1 (nb <= 256) in-LDS; off2 = off_raw + prefix; writes
// sentinel off2[n2]; writes only the phantom TAIL slots of each padded segment.
// ---------------------------------------------------------------------------
__global__ void scan3_tails(const int* __restrict__ off_raw, const int* __restrict__ bs1,
                            int nb, int n2, int* __restrict__ off2,
                            const int* __restrict__ deg,
                            int Np, int Na, int* __restrict__ srcu) {
    __shared__ int pf[SCAN_T];
    int t = threadIdx.x;
    pf[t] = (t < nb) ? bs1[t] : 0;
    __syncthreads();
    for (int off = 1; off < SCAN_T; off <<= 1) {
        int x = (t >= off) ? pf[t - off] : 0;
        __syncthreads();
        pf[t] += x;
        __syncthreads();
    }
    int i = blockIdx.x * 256 + t;
    if (i < n2) {
        int g = i >> 10;
        int o = off_raw[i] + (g ? pf[g - 1] : 0);
        off2[i] = o;
        int dgi = deg[i];
        int padded = (dgi + 3) & ~3;
        int ph = (i < Np) ? Na : Np;
        for (int k = dgi; k < padded; ++k) srcu[o + k] = ph;
    }
    if (blockIdx.x == 0 && t == 0) off2[n2] = pf[nb - 1];
}

// ---------------------------------------------------------------------------
// MFMA projection body (two-barrier, coalesced block-wide staging).
// xs rows: [128 bf16 msg][8 f32 src-side scores]. a_d arrays stay separate.
// ---------------------------------------------------------------------------
template <int NSC>
__device__ void proj_body(unsigned short* xt, int bid,
                          const float* __restrict__ x, int nrows,
                          const unsigned short* __restrict__ WlinP, const float* __restrict__ blin,
                          const unsigned short* __restrict__ WsrcP,
                          const unsigned short* __restrict__ VscP,
                          unsigned short* __restrict__ xs,
                          float* __restrict__ ad0, float* __restrict__ ad1) {
    int t = threadIdx.x;
    int lane = t & 63, w = t >> 6;
    long row0 = (long)bid * BM;
    for (int it = 0; it < 16; ++it) {
        int idx2 = t + it * 256;
        int r = idx2 >> 6, cp = idx2 & 63;
        long gr = row0 + r;
        float v0 = 0.f, v1 = 0.f;
        if (gr < nrows) { v0 = x[gr * DHID + 2 * cp]; v1 = x[gr * DHID + 2 * cp + 1]; }
        *reinterpret_cast<uint32_t*>(&xt[r * LDST + 2 * cp]) = pack2bf(v0, v1);
    }
    __syncthreads();
    int arow = w * 16 + (lane & 15);
    int koff = (lane >> 4) << 3;
    short8 af[4];
#pragma unroll
    for (int kk = 0; kk < 4; ++kk)
        af[kk] = *reinterpret_cast<const short8*>(&xt[arow * LDST + kk * 32 + koff]);
    const short8* Bl = reinterpret_cast<const short8*>(WlinP);
    f32x4 acc[8];
#pragma unroll
    for (int nt = 0; nt < 8; ++nt) {
        f32x4 a = {0.f, 0.f, 0.f, 0.f};
#pragma unroll
        for (int kk = 0; kk < 4; ++kk)
            a = __builtin_amdgcn_mfma_f32_16x16x32_bf16(af[kk], Bl[(nt * 4 + kk) * 64 + lane], a, 0, 0, 0);
        acc[nt] = a;
    }
    __syncthreads();
    int orow = w * 16 + ((lane >> 4) << 2);
    int ccol = lane & 15;
#pragma unroll
    for (int nt = 0; nt < 8; ++nt) {
        float b = blin[nt * 16 + ccol];
#pragma unroll
        for (int r = 0; r < 4; ++r) {
            float e = fmaxf(acc[nt][r] + b, 0.f);
            xt[(orow + r) * LDST + nt * 16 + ccol] = f2bf(e);
        }
    }
    __syncthreads();
#pragma unroll
    for (int kk = 0; kk < 4; ++kk)
        af[kk] = *reinterpret_cast<const short8*>(&xt[arow * LDST + kk * 32 + koff]);
    const short8* Bs = reinterpret_cast<const short8*>(WsrcP);
#pragma unroll
    for (int nt = 0; nt < 8; ++nt) {
        f32x4 a = {0.f, 0.f, 0.f, 0.f};
#pragma unroll
        for (int kk = 0; kk < 4; ++kk)
            a = __builtin_amdgcn_mfma_f32_16x16x32_bf16(af[kk], Bs[(nt * 4 + kk) * 64 + lane], a, 0, 0, 0);
        acc[nt] = a;
    }
    const short8* Bv = reinterpret_cast<const short8*>(VscP);
    f32x4 sacc0 = {0.f, 0.f, 0.f, 0.f}, sacc1 = {0.f, 0.f, 0.f, 0.f};
#pragma unroll
    for (int kk = 0; kk < 4; ++kk)
        sacc0 = __builtin_amdgcn_mfma_f32_16x16x32_bf16(af[kk], Bv[kk * 64 + lane], sacc0, 0, 0, 0);
    if (NSC > 1) {
#pragma unroll
        for (int kk = 0; kk < 4; ++kk)
            sacc1 = __builtin_amdgcn_mfma_f32_16x16x32_bf16(af[kk], Bv[(4 + kk) * 64 + lane], sacc1, 0, 0, 0);
    }
#pragma unroll
    for (int nt = 0; nt < 8; ++nt) {
#pragma unroll
        for (int r = 0; r < 4; ++r) {
            long gr = row0 + orow + r;
            if (gr < nrows) xs[gr * XST + nt * 16 + ccol] = f2bf(acc[nt][r]);
        }
    }
#pragma unroll
    for (int st = 0; st < NSC; ++st) {
        int scol = st * 16 + ccol;
        int h = scol & 7, which = scol >> 3;
        f32x4 s = (st == 0) ? sacc0 : sacc1;
#pragma unroll
        for (int r = 0; r < 4; ++r) {
            long gr = row0 + orow + r;
            if (gr >= nrows) continue;
            if (NSC == 2) {
                if (which == 0) ad0[gr * H + h] = s[r];
                else if (which == 1)
                    *reinterpret_cast<float*>(xs + gr * XST + 128 + 2 * h) = s[r];
                else if (which == 2) ad1[gr * H + h] = s[r];
                // which == 3: zero padding column — skip
            } else {
                if (which == 0)
                    *reinterpret_cast<float*>(xs + gr * XST + 128 + 2 * h) = s[r];
                // which == 1: zero padding column — skip
            }
        }
    }
}

// ---------------------------------------------------------------------------
// K4 MEGA: proj_paper, proj_author, then atomic-free scatter (MLP-4).
// ---------------------------------------------------------------------------
struct MegaArgs {
    const float* x_p; int Np;
    const unsigned short* WlinP_p; const float* blp;
    const unsigned short* WsrcP_c; const unsigned short* VscP_p;
    unsigned short* xs_c; float *a_d_w, *a_d_c;
    const float* x_a; int Na;
    const unsigned short* WlinP_a; const float* bla;
    const unsigned short* WsrcP_w; const unsigned short* VscP_a;
    unsigned short* xs_w;
    const int *src_w, *dst_w, *src_c, *dst_c;
    int Ew, Ec;
    const int *off2, *rank;
    int* srcu;
    int PB, AB;
};

__global__ __launch_bounds__(256) void mega(MegaArgs a) {
    __shared__ unsigned short xt[BM * LDST];
    int b = blockIdx.x;
    if (b < a.PB) {
        proj_body<2>(xt, b, a.x_p, a.Np, a.WlinP_p, a.blp, a.WsrcP_c, a.VscP_p,
                     a.xs_c, a.a_d_w, a.a_d_c);
        return;
    }
    if (b < a.PB + a.AB) {
        proj_body<1>(xt, b - a.PB, a.x_a, a.Na, a.WlinP_a, a.bla, a.WsrcP_w, a.VscP_a,
                     a.xs_w, nullptr, nullptr);
        return;
    }
    int base = (b - a.PB - a.AB) * 1024 + threadIdx.x;
    int E = a.Ew + a.Ec;
    int s[4], di[4], rk[4];
    bool val[4];
#pragma unroll
    for (int j = 0; j < 4; ++j) {
        int i = base + j * 256;
        val[j] = i < E;
        s[j] = di[j] = rk[j] = 0;
        if (val[j]) {
            if (i < a.Ew) { s[j] = a.src_w[i]; di[j] = a.dst_w[i]; }
            else { int q = i - a.Ew; s[j] = a.src_c[q]; di[j] = a.Np + a.dst_c[q]; }
            rk[j] = a.rank[i];
        }
    }
    int pos[4];
#pragma unroll
    for (int j = 0; j < 4; ++j)
        if (val[j]) pos[j] = a.off2[di[j]] + rk[j];
#pragma unroll
    for (int j = 0; j < 4; ++j)
        if (val[j]) a.srcu[pos[j]] = s[j];
}

// ---------------------------------------------------------------------------
// Gather ∥ author fill, STATIC grid-stride persistent blocks (no in-loop
// barriers — per-wave independence is what hides the random-load latency).
// Stats fused in-register; block LDS reduce + 128x2 atomics at the end.
// ---------------------------------------------------------------------------
#define FILLB 391
#define GATB 2048
__global__ __launch_bounds__(256) void gat_gather(
    const int* __restrict__ off, const int* __restrict__ srcu,
    const float* __restrict__ a_d_w, const float* __restrict__ a_d_c,
    const unsigned short* __restrict__ xs_w, const unsigned short* __restrict__ xs_c,
    uint32_t* __restrict__ gatb, int Np, int nselfw, int ngroups,
    float* __restrict__ colsum, float* __restrict__ colsumsq,
    const float* __restrict__ row_a, float4* __restrict__ outa, long n4) {
    if (blockIdx.x < FILLB) {
        long i = (long)blockIdx.x * 256 + threadIdx.x;
        long stride = (long)FILLB * 256;
        const float4* r4 = reinterpret_cast<const float4*>(row_a);
        for (; i < n4; i += stride) outa[i] = r4[i & 31];
        return;
    }
    __shared__ float red1[4 * DHID], red2[4 * DHID];
    int t = threadIdx.x;
    int l = t & 63;
    int rg = t >> 6;
    int h = l >> 3;
    int sco = 128 + 2 * h;
    int gstride = gridDim.x - FILLB;
    float cs0 = 0.f, cs1 = 0.f, cq0 = 0.f, cq1 = 0.f;
    for (int g = blockIdx.x - FILLB; g < ngroups; g += gstride) {
        int d = g * 4 + rg;
        if (d >= Np) continue;
        int iw = off[d], w1 = off[d + 1];
        int ic = off[Np + d], c1 = off[Np + d + 1];
        float adw = a_d_w[(long)d * H + h];
        float adc = a_d_c[(long)d * H + h];
        float denw = 0.f, n0w = 0.f, n1w = 0.f;
        float denc = 0.f, n0c = 0.f, n1c = 0.f;
        if (d < nselfw) {
            const unsigned short* r = xs_w + (long)d * XST;
            float e = *reinterpret_cast<const float*>(r + sco) + adw;
            e = e > 0.f ? e : NEG_SLOPE * e;
            float p = __expf(e);
            uint32_t v = *reinterpret_cast<const uint32_t*>(r + 2 * l);
            denw += p; n0w += p * bflo(v); n1w += p * bfhi(v);
        }
        {
            const unsigned short* r = xs_c + (long)d * XST;
            float e = *reinterpret_cast<const float*>(r + sco) + adc;
            e = e > 0.f ? e : NEG_SLOPE * e;
            float p = __expf(e);
            uint32_t v = *reinterpret_cast<const uint32_t*>(r + 2 * l);
            denc += p; n0c += p * bflo(v); n1c += p * bfhi(v);
        }
        while (iw < w1 || ic < c1) {
            bool hw = iw < w1, hc = ic < c1;
            int4 sw, sc;
            if (hw) sw = *reinterpret_cast<const int4*>(srcu + iw);
            if (hc) sc = *reinterpret_cast<const int4*>(srcu + ic);
            float ew[4], ec[4];
            uint32_t vw[4], vc[4];
            if (hw) {
                const unsigned short* r0 = xs_w + (long)sw.x * XST;
                const unsigned short* r1 = xs_w + (long)sw.y * XST;
                const unsigned short* r2 = xs_w + (long)sw.z * XST;
                const unsigned short* r3 = xs_w + (long)sw.w * XST;
                ew[0] = *reinterpret_cast<const float*>(r0 + sco);
                ew[1] = *reinterpret_cast<const float*>(r1 + sco);
                ew[2] = *reinterpret_cast<const float*>(r2 + sco);
                ew[3] = *reinterpret_cast<const float*>(r3 + sco);
                vw[0] = *reinterpret_cast<const uint32_t*>(r0 + 2 * l);
                vw[1] = *reinterpret_cast<const uint32_t*>(r1 + 2 * l);
                vw[2] = *reinterpret_cast<const uint32_t*>(r2 + 2 * l);
                vw[3] = *reinterpret_cast<const uint32_t*>(r3 + 2 * l);
            }
            if (hc) {
                const unsigned short* r0 = xs_c + (long)sc.x * XST;
                const unsigned short* r1 = xs_c + (long)sc.y * XST;
                const unsigned short* r2 = xs_c + (long)sc.z * XST;
                const unsigned short* r3 = xs_c + (long)sc.w * XST;
                ec[0] = *reinterpret_cast<const float*>(r0 + sco);
                ec[1] = *reinterpret_cast<const float*>(r1 + sco);
                ec[2] = *reinterpret_cast<const float*>(r2 + sco);
                ec[3] = *reinterpret_cast<const float*>(r3 + sco);
                vc[0] = *reinterpret_cast<const uint32_t*>(r0 + 2 * l);
                vc[1] = *reinterpret_cast<const uint32_t*>(r1 + 2 * l);
                vc[2] = *reinterpret_cast<const uint32_t*>(r2 + 2 * l);
                vc[3] = *reinterpret_cast<const uint32_t*>(r3 + 2 * l);
            }
            if (hw) {
#pragma unroll
                for (int j = 0; j < 4; ++j) {
                    float e = ew[j] + adw;
                    e = e > 0.f ? e : NEG_SLOPE * e;
                    float p = __expf(e);
                    denw += p;
                    n0w += p * bflo(vw[j]);
                    n1w += p * bfhi(vw[j]);
                }
                iw += 4;
            }
            if (hc) {
#pragma unroll
                for (int j = 0; j < 4; ++j) {
                    float e = ec[j] + adc;
                    e = e > 0.f ? e : NEG_SLOPE * e;
                    float p = __expf(e);
                    denc += p;
                    n0c += p * bflo(vc[j]);
                    n1c += p * bfhi(vc[j]);
                }
                ic += 4;
            }
        }
        float rw = 1.f / (denw + 1e-16f);
        float rc = 1.f / (denc + 1e-16f);
        float o0 = n0w * rw + n0c * rc;
        float o1 = n1w * rw + n1c * rc;
        gatb[(long)d * 64 + l] = pack2bf(o0, o1);
        cs0 += o0; cs1 += o1;
        cq0 += o0 * o0; cq1 += o1 * o1;
    }
    red1[rg * DHID + 2 * l] = cs0;
    red1[rg * DHID + 2 * l + 1] = cs1;
    red2[rg * DHID + 2 * l] = cq0;
    red2[rg * DHID + 2 * l + 1] = cq1;
    __syncthreads();
    if (t < DHID) {
        float s1 = red1[t] + red1[DHID + t] + red1[2 * DHID + t] + red1[3 * DHID + t];
        float s2 = red2[t] + red2[DHID + t] + red2[2 * DHID + t] + red2[3 * DHID + t];
        atomAddF(colsum + t, s1);
        atomAddF(colsumsq + t, s2);
    }
}

// ---------------------------------------------------------------------------
// K6: final_mfma — stats from raw Σgat, Σgat² with analytic bsum correction:
//   mu = Σg/Np + b;  E[x²] = Σg²/Np + 2b·Σg/Np + b²;  var = E[x²] − mu²·ms(2−ms)
// ---------------------------------------------------------------------------
__global__ __launch_bounds__(256) void final_fill(
    const uint32_t* __restrict__ gatb, const float* __restrict__ bsum,
    const float* __restrict__ colsum, const float* __restrict__ colsumsq,
    const float* __restrict__ gnw, const float* __restrict__ gnb,
    const float* __restrict__ gnm,
    const unsigned short* __restrict__ W2P, const float* __restrict__ b2,
    float* __restrict__ out, int Np) {
    __shared__ unsigned short xt[BM * LDST];
    __shared__ float cscale[DHID], cshift[DHID];
    int b = blockIdx.x;
    int t = threadIdx.x;
    int lane = t & 63, w = t >> 6;
    long row0 = (long)b * BM;
    if (t < DHID) {
        float invN = 1.f / (float)Np;
        float bb = bsum[t];
        float sg = colsum[t] * invN;           // E[gat]
        float eq = colsumsq[t] * invN;         // E[gat^2]
        float mu = sg + bb;
        float ex2 = eq + 2.f * bb * sg + bb * bb;
        float ms = gnm[t];
        float var = ex2 - mu * mu * ms * (2.f - ms);
        float sc = gnw[t] * rsqrtf(var + GN_EPS);
        cscale[t] = sc;
        cshift[t] = (bb - ms * mu) * sc + gnb[t];
    }
    __syncthreads();
    int wrow0 = w * 16;
    float cs0 = cscale[2 * lane], cf0 = cshift[2 * lane];
    float cs1 = cscale[2 * lane + 1], cf1 = cshift[2 * lane + 1];
    for (int it = 0; it < 16; ++it) {
        int r = wrow0 + it;
        long gr = row0 + r;
        float v0 = 0.f, v1 = 0.f;
        if (gr < Np) {
            uint32_t u = gatb[gr * 64 + lane];
            v0 = bflo(u) * cs0 + cf0;
            v1 = bfhi(u) * cs1 + cf1;
        }
        *reinterpret_cast<uint32_t*>(&xt[r * LDST + 2 * lane]) = pack2bf(v0, v1);
    }
    int arow = wrow0 + (lane & 15);
    int koff = (lane >> 4) << 3;
    short8 af[4];
#pragma unroll
    for (int kk = 0; kk < 4; ++kk)
        af[kk] = *reinterpret_cast<const short8*>(&xt[arow * LDST + kk * 32 + koff]);
    const short8* Bw = reinterpret_cast<const short8*>(W2P);
    int orow = wrow0 + ((lane >> 4) << 2);
    int ccol = lane & 15;
#pragma unroll
    for (int nt = 0; nt < 8; ++nt) {
        f32x4 a = {0.f, 0.f, 0.f, 0.f};
#pragma unroll
        for (int kk = 0; kk < 4; ++kk)
            a = __builtin_amdgcn_mfma_f32_16x16x32_bf16(af[kk], Bw[(nt * 4 + kk) * 64 + lane], a, 0, 0, 0);
        float bb = b2[nt * 16 + ccol];
#pragma unroll
        for (int r = 0; r < 4; ++r) {
            long gr = row0 + orow + r;
            if (gr < Np) out[gr * DHID + nt * 16 + ccol] = a[r] + bb;
        }
    }
}

// ---------------------------------------------------------------------------
extern "C" void kernel_launch(void* const* d_in, const int* in_sizes, int n_in,
                              void* d_out, int out_size, void* d_ws, size_t ws_size,
                              hipStream_t stream) {
    const float* x_p   = (const float*)d_in[0];
    const float* x_a   = (const float*)d_in[1];
    const int*   e_w   = (const int*)d_in[2];
    const int*   e_c   = (const int*)d_in[3];
    const float* Wlp   = (const float*)d_in[4];
    const float* blp   = (const float*)d_in[5];
    const float* Wla   = (const float*)d_in[6];
    const float* bla   = (const float*)d_in[7];
    const float* Wsw   = (const float*)d_in[8];
    const float* Wdw   = (const float*)d_in[9];
    const float* asw   = (const float*)d_in[10];
    const float* adw   = (const float*)d_in[11];
    const float* bw    = (const float*)d_in[12];
    const float* Wsc   = (const float*)d_in[13];
    const float* Wdc   = (const float*)d_in[14];
    const float* asc   = (const float*)d_in[15];
    const float* adc   = (const float*)d_in[16];
    const float* bc    = (const float*)d_in[17];
    const float* gnw_p = (const float*)d_in[18];
    const float* gnb_p = (const float*)d_in[19];
    const float* gnm_p = (const float*)d_in[20];
    const float* gnb_a = (const float*)d_in[22];
    const float* W2p   = (const float*)d_in[24];
    const float* b2p   = (const float*)d_in[25];
    const float* W2a   = (const float*)d_in[26];
    const float* b2a   = (const float*)d_in[27];

    int Np = in_sizes[0] / DHID;
    int Na = in_sizes[1] / DHID;
    int Ew = in_sizes[2] / 2;
    int Ec = in_sizes[3] / 2;
    int nself_w = Na < Np ? Na : Np;
    int tot_edges = Ew + Ec;
    int maxTot = tot_edges + 6 * Np + 8;

    float* ws = (float*)d_ws;
    uint32_t* gatb = (uint32_t*)ws;                    // Np*64 (bf16 pairs)
    float* a_d_w = (float*)(gatb + (size_t)Np * 64);   // Np*8
    float* a_d_c = a_d_w + (size_t)Np * H;             // Np*8
    float* bsum  = a_d_c + (size_t)Np * H;             // 128
    float* row_a = bsum + DHID;                        // 128
    float* colsum   = row_a + DHID;                    // 128
    float* colsumsq = colsum + DHID;                   // 128
    int*   deg   = (int*)(colsumsq + DHID);            // 2*Np (memset)
    int* off_raw = deg + 2 * Np;                       // 2*Np
    int* off2    = off_raw + 2 * Np;                   // 2*Np + 1
    int* bs1     = off2 + 2 * Np + 1;                  // 512
    uintptr_t up = (uintptr_t)(bs1 + 512);
    up = (up + 15) & ~(uintptr_t)15;
    int* srcu = (int*)up;                              // maxTot
    int* rank = srcu + maxTot;                         // tot_edges
    unsigned short* xs_w = (unsigned short*)(rank + tot_edges);  // (Na+1)*XST
    unsigned short* xs_c = xs_w + (size_t)(Na + 1) * XST;        // (Np+1)*XST
    up = (uintptr_t)(xs_c + (size_t)(Np + 1) * XST);
    up = (up + 15) & ~(uintptr_t)15;
    unsigned short* WlinP_p = (unsigned short*)up;
    unsigned short* WsrcP_c = WlinP_p + 16384;
    unsigned short* WlinP_a = WsrcP_c + 16384;
    unsigned short* WsrcP_w = WlinP_a + 16384;
    unsigned short* W2P_p   = WsrcP_w + 16384;
    unsigned short* VscP_p  = W2P_p + 16384;
    unsigned short* VscP_a  = VscP_p + 4096;

    hipMemsetAsync(deg, 0, 2 * (size_t)Np * sizeof(int), stream);

    int HB = (tot_edges + 2047) / 2048;      // MLP-8: 8 edges/thread
    {
        PrepHist pa;
        pa.Wlp = Wlp; pa.Wsc = Wsc; pa.Wla = Wla; pa.Wsw = Wsw; pa.W2p = W2p;
        pa.Wdw = Wdw; pa.adw = adw; pa.asc_ = asc; pa.Wdc = Wdc; pa.adc_ = adc; pa.asw_ = asw;
        pa.WlinP_p = WlinP_p; pa.WsrcP_c = WsrcP_c; pa.WlinP_a = WlinP_a;
        pa.WsrcP_w = WsrcP_w; pa.W2P_p = W2P_p; pa.VscP_p = VscP_p; pa.VscP_a = VscP_a;
        pa.bw = bw; pa.bc = bc; pa.gnb_a = gnb_a; pa.W2a = W2a; pa.b2a = b2a;
        pa.bsum = bsum; pa.row_a = row_a; pa.colsum = colsum; pa.colsumsq = colsumsq;
        pa.xs_w_ph = xs_w + (size_t)Na * XST;
        pa.xs_c_ph = xs_c + (size_t)Np * XST;
        pa.dst_w = e_w + Ew; pa.dst_c = e_c + Ec;
        pa.deg = deg; pa.rank = rank;
        pa.Ew = Ew; pa.Ec = Ec;
        pa.Np = Np; pa.HB0 = 57;
        prep_hist<<<57 + HB, 256, 0, stream>>>(pa);
    }

    int n2 = 2 * Np;
    int nb = (n2 + SCAN_T * SCAN_I - 1) / (SCAN_T * SCAN_I);   // must be <= 256
    scan1<<<nb, SCAN_T, 0, stream>>>(deg, n2, off_raw, bs1);

    scan3_tails<<<(n2 + 255) / 256, 256, 0, stream>>>(
        off_raw, bs1, nb, n2, off2, deg, Np, Na, srcu);

    {
        MegaArgs ma;
        ma.x_p = x_p; ma.Np = Np; ma.WlinP_p = WlinP_p; ma.blp = blp;
        ma.WsrcP_c = WsrcP_c; ma.VscP_p = VscP_p;
        ma.xs_c = xs_c; ma.a_d_w = a_d_w; ma.a_d_c = a_d_c;
        ma.x_a = x_a; ma.Na = Na; ma.WlinP_a = WlinP_a; ma.bla = bla;
        ma.WsrcP_w = WsrcP_w; ma.VscP_a = VscP_a;
        ma.xs_w = xs_w;
        ma.src_w = e_w; ma.dst_w = e_w + Ew; ma.src_c = e_c; ma.dst_c = e_c + Ec;
        ma.Ew = Ew; ma.Ec = Ec;
        ma.off2 = off2; ma.rank = rank; ma.srcu = srcu;
        ma.PB = (Np + BM - 1) / BM;
        ma.AB = (Na + BM - 1) / BM;
        int SB = (tot_edges + 1023) / 1024;
        mega<<<ma.PB + ma.AB + SB, 256, 0, stream>>>(ma);
    }

    {
        long n4 = (long)Na * DHID / 4;
        int ngroups = (Np + 3) / 4;
        int GB = ngroups < GATB ? ngroups : GATB;
        gat_gather<<<FILLB + GB, 256, 0, stream>>>(
            off2, srcu, a_d_w, a_d_c, xs_w, xs_c, gatb, Np, nself_w, ngroups,
            colsum, colsumsq,
            row_a, (float4*)((float*)d_out + (size_t)Np * DHID), n4);
    }

    final_fill<<<(Np + BM - 1) / BM, 256, 0, stream>>>(
        gatb, bsum, colsum, colsumsq, gnw_p, gnb_p, gnm_p, W2P_p, b2p,
        (float*)d_out, Np);
}